// Round 1
// baseline (1277.333 us; speedup 1.0000x reference)
//
#include <hip/hip_runtime.h>
#include <math.h>

// 2-layer GAT (PyG GATConv semantics) for N=50000, E=1.6M, IN=256.
// Layer 1: 256 -> 8 heads x 8 ch (concat 64) + bias + ELU
// Layer 2: 64  -> 4 heads x 16 ch (mean over heads) + bias
//
// Pipeline per layer:
//   K1 node_transform: xl = x@W, asrc[n,h], adst[n,h]
//   K2 edge_max:       amax[dst,h] = segmax(leakyrelu(asrc[src]+adst[dst]))
//   K3 edge_aggregate: acc[dst,m] += p*xl[src,m], denom[dst,h] += p   (fused)
//   K4 finalize:       divide by denom, add bias, activation
// Self-loops synthesized on the fly (e >= E -> src=dst=e-E).

#define LEAK 0.2f
#define EPSV 1e-16f

__device__ __forceinline__ unsigned enc_f(float f) {
    unsigned u = __float_as_uint(f);
    return (u & 0x80000000u) ? ~u : (u | 0x80000000u);
}
__device__ __forceinline__ float dec_f(unsigned u) {
    unsigned b = (u & 0x80000000u) ? (u ^ 0x80000000u) : ~u;
    return __uint_as_float(b);
}

// One block (64 threads) per node: xl row + per-head attention logits.
template<int K, int H, int CH>
__global__ __launch_bounds__(64)
void node_transform(const float* __restrict__ x, const float* __restrict__ W,
                    const float* __restrict__ a_src, const float* __restrict__ a_dst,
                    float* __restrict__ xl, float* __restrict__ asrc,
                    float* __restrict__ adst, int n)
{
    constexpr int M = H * CH;           // 64 in both layers
    __shared__ float xs[K];
    __shared__ float row[M];
    int node = blockIdx.x;
    if (node >= n) return;
    int t = threadIdx.x;
    for (int k = t; k < K; k += 64) xs[k] = x[(size_t)node * K + k];
    __syncthreads();
    float acc = 0.f;
    #pragma unroll 8
    for (int k = 0; k < K; ++k) acc = fmaf(xs[k], W[k * M + t], acc);
    xl[(size_t)node * M + t] = acc;
    row[t] = acc;
    __syncthreads();
    if (t < H) {
        float s = 0.f, d = 0.f;
        #pragma unroll
        for (int c = 0; c < CH; ++c) {
            float v = row[t * CH + c];
            s = fmaf(v, a_src[t * CH + c], s);
            d = fmaf(v, a_dst[t * CH + c], d);
        }
        asrc[node * H + t] = s;
        adst[node * H + t] = d;
    }
}

// One thread per (edge, head): segment max via monotonic-uint atomicMax.
template<int H>
__global__ __launch_bounds__(256)
void edge_max(const int* __restrict__ src, const int* __restrict__ dst, int E, int n,
              const float* __restrict__ asrc, const float* __restrict__ adst,
              unsigned* __restrict__ amax_u)
{
    int total = (E + n) * H;
    for (int i = blockIdx.x * 256 + threadIdx.x; i < total; i += gridDim.x * 256) {
        int e = i / H, h = i - e * H;
        int s, d;
        if (e < E) { s = src[e]; d = dst[e]; } else { s = d = e - E; }
        float al = asrc[s * H + h] + adst[d * H + h];
        al = (al >= 0.f) ? al : LEAK * al;
        atomicMax(&amax_u[d * H + h], enc_f(al));
    }
}

// One 64-lane group per edge; lane = output channel m = h*CH + c.
// Fused: unnormalized weighted aggregation + denominator accumulation.
template<int H, int CH>
__global__ __launch_bounds__(256)
void edge_aggregate(const int* __restrict__ src, const int* __restrict__ dst, int E, int n,
                    const float* __restrict__ asrc, const float* __restrict__ adst,
                    const unsigned* __restrict__ amax_u, float* __restrict__ denom,
                    const float* __restrict__ xl, float* __restrict__ acc)
{
    constexpr int M = H * CH;           // 64
    int ET = E + n;
    int lane = threadIdx.x & 63;
    int h = lane / CH;
    int groups = gridDim.x * (blockDim.x >> 6);
    for (int e = blockIdx.x * (blockDim.x >> 6) + (threadIdx.x >> 6); e < ET; e += groups) {
        int s, d;
        if (e < E) { s = src[e]; d = dst[e]; } else { s = d = e - E; }
        float al = asrc[s * H + h] + adst[d * H + h];
        al = (al >= 0.f) ? al : LEAK * al;
        float p = expf(al - dec_f(amax_u[d * H + h]));
        if ((lane & (CH - 1)) == 0) atomicAdd(&denom[d * H + h], p);
        atomicAdd(&acc[(size_t)d * M + lane], p * xl[(size_t)s * M + lane]);
    }
}

// Layer 1 finalize: h = elu(acc/denom + b1), in place.
template<int H, int CH>
__global__ __launch_bounds__(256)
void finalize_layer1(float* __restrict__ acc, const float* __restrict__ denom,
                     const float* __restrict__ b, int n)
{
    constexpr int M = H * CH;
    int i = blockIdx.x * 256 + threadIdx.x;
    if (i >= n * M) return;
    int m = i & (M - 1);
    int node = i / M;
    float dn = fmaxf(denom[node * H + m / CH], EPSV);
    float v = acc[i] / dn + b[m];
    acc[i] = (v > 0.f) ? v : expm1f(v);
}

// Layer 2 finalize: out[n,c] = mean_h(acc/denom) + b2[c].
__global__ __launch_bounds__(256)
void finalize_layer2(const float* __restrict__ acc, const float* __restrict__ denom,
                     const float* __restrict__ b, float* __restrict__ out, int n)
{
    int i = blockIdx.x * 256 + threadIdx.x;   // n*16
    if (i >= n * 16) return;
    int node = i >> 4, c = i & 15;
    float s = 0.f;
    #pragma unroll
    for (int h = 0; h < 4; ++h)
        s += acc[node * 64 + h * 16 + c] / fmaxf(denom[node * 4 + h], EPSV);
    out[i] = 0.25f * s + b[c];
}

extern "C" void kernel_launch(void* const* d_in, const int* in_sizes, int n_in,
                              void* d_out, int out_size, void* d_ws, size_t ws_size,
                              hipStream_t stream)
{
    const float* x      = (const float*)d_in[0];
    const int*   ei     = (const int*)d_in[1];
    const float* W1     = (const float*)d_in[2];
    const float* a_src1 = (const float*)d_in[3];
    const float* a_dst1 = (const float*)d_in[4];
    const float* b1     = (const float*)d_in[5];
    const float* W2     = (const float*)d_in[6];
    const float* a_src2 = (const float*)d_in[7];
    const float* a_dst2 = (const float*)d_in[8];
    const float* b2     = (const float*)d_in[9];
    float* out = (float*)d_out;

    const int n = in_sizes[0] / 256;     // 50000
    const int E = in_sizes[1] / 2;       // 1600000
    const int ET = E + n;

    const int* src = ei;
    const int* dst = ei + E;

    // Workspace layout (floats)
    size_t N64 = (size_t)n * 64;
    size_t N8  = (size_t)n * 8;
    float*    xl    = (float*)d_ws;           // N*64
    float*    hbuf  = xl + N64;               // N*64  (layer1 acc, then h)
    float*    acc2  = hbuf + N64;             // N*64  (layer2 acc)
    float*    asrc  = acc2 + N64;             // N*8
    float*    adst  = asrc + N8;              // N*8
    unsigned* amaxu = (unsigned*)(adst + N8); // N*8
    float*    denom = (float*)(amaxu + N8);   // N*8
    (void)ws_size; (void)n_in; (void)out_size;

    // ---------------- Layer 1: 256 -> 8x8, concat ----------------
    hipMemsetAsync(hbuf, 0, N64 * sizeof(float), stream);
    hipMemsetAsync(amaxu, 0, N8 * sizeof(unsigned), stream);
    hipMemsetAsync(denom, 0, N8 * sizeof(float), stream);

    node_transform<256, 8, 8><<<n, 64, 0, stream>>>(x, W1, a_src1, a_dst1,
                                                    xl, asrc, adst, n);
    {
        int total = ET * 8;
        int blocks = (total + 255) / 256;
        edge_max<8><<<blocks, 256, 0, stream>>>(src, dst, E, n, asrc, adst, amaxu);
    }
    {
        int blocks = (ET + 3) / 4;       // 4 edges per 256-thread block
        edge_aggregate<8, 8><<<blocks, 256, 0, stream>>>(src, dst, E, n, asrc, adst,
                                                         amaxu, denom, xl, hbuf);
    }
    {
        int total = (int)N64;
        finalize_layer1<8, 8><<<(total + 255) / 256, 256, 0, stream>>>(hbuf, denom, b1, n);
    }

    // ---------------- Layer 2: 64 -> 4x16, mean ----------------
    hipMemsetAsync(acc2, 0, N64 * sizeof(float), stream);
    hipMemsetAsync(amaxu, 0, N8 * sizeof(unsigned), stream);
    hipMemsetAsync(denom, 0, N8 * sizeof(float), stream);

    node_transform<64, 4, 16><<<n, 64, 0, stream>>>(hbuf, W2, a_src2, a_dst2,
                                                    xl, asrc, adst, n);
    {
        int total = ET * 4;
        int blocks = (total + 255) / 256;
        edge_max<4><<<blocks, 256, 0, stream>>>(src, dst, E, n, asrc, adst, amaxu);
    }
    {
        int blocks = (ET + 3) / 4;
        edge_aggregate<4, 16><<<blocks, 256, 0, stream>>>(src, dst, E, n, asrc, adst,
                                                          amaxu, denom, xl, acc2);
    }
    {
        int total = n * 16;
        finalize_layer2<<<(total + 255) / 256, 256, 0, stream>>>(acc2, denom, b2, out, n);
    }
}

// Round 2
// 494.114 us; speedup vs baseline: 2.5851x; 2.5851x over previous
//
#include <hip/hip_runtime.h>
#include <math.h>

// 2-layer GAT (PyG GATConv semantics) for N=50000, E=1.6M, IN=256.
// Round 2: CSR-based aggregation (counting sort by dst), no atomics in the
// hot path, softmax without max-subtraction (numerically safe here, exactly
// equivalent in real arithmetic), fully fused normalize+bias+activation.
//
// Pipeline:
//   once: hist(dst) -> 3-kernel exclusive scan -> scatter (2-byte src ids)
//   per layer:
//     node_transform: xl = x@W, asrc[n,h], adst[n,h]
//     aggregate_csr : per-node wave; acc[m] = sum_e exp(a_e)*xl[src_e,m];
//                     fused /denom, +bias, ELU (L1) or head-mean (L2)

#define LEAK 0.2f
#define EPSV 1e-16f

// ---------------- node transform (unchanged from round 1) ----------------
template<int K, int H, int CH>
__global__ __launch_bounds__(64)
void node_transform(const float* __restrict__ x, const float* __restrict__ W,
                    const float* __restrict__ a_src, const float* __restrict__ a_dst,
                    float* __restrict__ xl, float* __restrict__ asrc,
                    float* __restrict__ adst, int n)
{
    constexpr int M = H * CH;           // 64 in both layers
    __shared__ float xs[K];
    __shared__ float row[M];
    int node = blockIdx.x;
    if (node >= n) return;
    int t = threadIdx.x;
    for (int k = t; k < K; k += 64) xs[k] = x[(size_t)node * K + k];
    __syncthreads();
    float acc = 0.f;
    #pragma unroll 8
    for (int k = 0; k < K; ++k) acc = fmaf(xs[k], W[k * M + t], acc);
    xl[(size_t)node * M + t] = acc;
    row[t] = acc;
    __syncthreads();
    if (t < H) {
        float s = 0.f, d = 0.f;
        #pragma unroll
        for (int c = 0; c < CH; ++c) {
            float v = row[t * CH + c];
            s = fmaf(v, a_src[t * CH + c], s);
            d = fmaf(v, a_dst[t * CH + c], d);
        }
        asrc[node * H + t] = s;
        adst[node * H + t] = d;
    }
}

// ---------------- CSR build: histogram, scan, scatter ----------------
__global__ __launch_bounds__(256)
void hist_kernel(const int* __restrict__ dst, int E, int* __restrict__ cnt)
{
    for (int e = blockIdx.x * 256 + threadIdx.x; e < E; e += gridDim.x * 256)
        atomicAdd(&cnt[dst[e]], 1);
}

#define SCAN_BLK 256
#define SCAN_ELEM 8   // 2048 elements per block

__global__ __launch_bounds__(SCAN_BLK)
void scan1_kernel(const int* __restrict__ cnt, int* __restrict__ part,
                  int* __restrict__ sums, int n)
{
    __shared__ int lds[SCAN_BLK];
    int base = blockIdx.x * (SCAN_BLK * SCAN_ELEM);
    int t = threadIdx.x;
    int v[SCAN_ELEM];
    int s = 0;
    #pragma unroll
    for (int j = 0; j < SCAN_ELEM; ++j) {
        int idx = base + t * SCAN_ELEM + j;
        v[j] = (idx < n) ? cnt[idx] : 0;
        s += v[j];
    }
    lds[t] = s;
    __syncthreads();
    for (int off = 1; off < SCAN_BLK; off <<= 1) {
        int a = (t >= off) ? lds[t - off] : 0;
        __syncthreads();
        lds[t] += a;
        __syncthreads();
    }
    int excl = lds[t] - s;
    if (t == SCAN_BLK - 1) sums[blockIdx.x] = lds[t];
    int run = excl;
    #pragma unroll
    for (int j = 0; j < SCAN_ELEM; ++j) {
        int idx = base + t * SCAN_ELEM + j;
        if (idx < n) part[idx] = run;
        run += v[j];
    }
}

__global__ void scan2_kernel(int* sums, int nb)
{
    if (threadIdx.x == 0 && blockIdx.x == 0) {
        int r = 0;
        for (int i = 0; i < nb; ++i) { int v = sums[i]; sums[i] = r; r += v; }
    }
}

__global__ __launch_bounds__(256)
void scan3_kernel(const int* __restrict__ part, const int* __restrict__ sums,
                  int* __restrict__ offs, int* __restrict__ cursor, int n, int E)
{
    int i = blockIdx.x * 256 + threadIdx.x;
    if (i < n) {
        int v = part[i] + sums[i / (SCAN_BLK * SCAN_ELEM)];
        offs[i] = v;
        cursor[i] = v;
    }
    if (i == 0) offs[n] = E;
}

__global__ __launch_bounds__(256)
void scatter_kernel(const int* __restrict__ src, const int* __restrict__ dst, int E,
                    int* __restrict__ cursor, unsigned short* __restrict__ ssrc)
{
    for (int e = blockIdx.x * 256 + threadIdx.x; e < E; e += gridDim.x * 256) {
        int p = atomicAdd(&cursor[dst[e]], 1);
        ssrc[p] = (unsigned short)src[e];
    }
}

// ---------------- fused CSR aggregation ----------------
// One 64-lane wave per destination node; lane = output element m = h*CH+c.
// MODE 1: write elu(acc/den + b[m])  -> hout[node*64+m]
// MODE 2: head-mean: out[node*16+c] = 0.25*sum_h(acc/den) + b[c]
template<int H, int CH, int MODE>
__global__ __launch_bounds__(256)
void aggregate_csr(const int* __restrict__ offs, const unsigned short* __restrict__ ssrc,
                   const float* __restrict__ asrc, const float* __restrict__ adst,
                   const float* __restrict__ xl, const float* __restrict__ b,
                   float* __restrict__ outp, int n)
{
    constexpr int M = H * CH;  // 64
    int wid = blockIdx.x * 4 + (threadIdx.x >> 6);
    if (wid >= n) return;
    int d = __builtin_amdgcn_readfirstlane(wid);
    int lane = threadIdx.x & 63;
    int h = lane / CH;

    float ad = adst[d * H + h];
    int beg = __builtin_amdgcn_readfirstlane(offs[d]);
    int end = __builtin_amdgcn_readfirstlane(offs[d + 1]);

    float acc = 0.f, den = 0.f;
    // self-loop (src == dst)
    {
        float al = asrc[d * H + h] + ad;
        al = (al >= 0.f) ? al : LEAK * al;
        float p = __expf(al);
        den += p;
        acc = fmaf(p, xl[(size_t)d * M + lane], acc);
    }
    int i = beg;
    for (; i + 4 <= end; i += 4) {
        int s0 = __builtin_amdgcn_readfirstlane(ssrc[i]);
        int s1 = __builtin_amdgcn_readfirstlane(ssrc[i + 1]);
        int s2 = __builtin_amdgcn_readfirstlane(ssrc[i + 2]);
        int s3 = __builtin_amdgcn_readfirstlane(ssrc[i + 3]);
        float a0 = asrc[s0 * H + h], a1 = asrc[s1 * H + h];
        float a2 = asrc[s2 * H + h], a3 = asrc[s3 * H + h];
        float x0 = xl[(size_t)s0 * M + lane], x1 = xl[(size_t)s1 * M + lane];
        float x2 = xl[(size_t)s2 * M + lane], x3 = xl[(size_t)s3 * M + lane];
        float l0 = a0 + ad; l0 = (l0 >= 0.f) ? l0 : LEAK * l0;
        float l1 = a1 + ad; l1 = (l1 >= 0.f) ? l1 : LEAK * l1;
        float l2 = a2 + ad; l2 = (l2 >= 0.f) ? l2 : LEAK * l2;
        float l3 = a3 + ad; l3 = (l3 >= 0.f) ? l3 : LEAK * l3;
        float p0 = __expf(l0), p1 = __expf(l1), p2 = __expf(l2), p3 = __expf(l3);
        den += p0 + p1 + p2 + p3;
        acc = fmaf(p0, x0, acc);
        acc = fmaf(p1, x1, acc);
        acc = fmaf(p2, x2, acc);
        acc = fmaf(p3, x3, acc);
    }
    for (; i < end; ++i) {
        int s = __builtin_amdgcn_readfirstlane(ssrc[i]);
        float al = asrc[s * H + h] + ad;
        al = (al >= 0.f) ? al : LEAK * al;
        float p = __expf(al);
        den += p;
        acc = fmaf(p, xl[(size_t)s * M + lane], acc);
    }

    float v = acc / fmaxf(den, EPSV);
    if (MODE == 1) {
        v += b[lane];
        outp[(size_t)d * M + lane] = (v > 0.f) ? v : expm1f(v);
    } else {
        // mean over H=4 heads: lane = h*16 + c; butterfly over head bits 4,5
        v += __shfl_xor(v, 16);
        v += __shfl_xor(v, 32);
        if (lane < 16) outp[(size_t)d * 16 + lane] = 0.25f * v + b[lane];
    }
}

// ---------------- host ----------------
extern "C" void kernel_launch(void* const* d_in, const int* in_sizes, int n_in,
                              void* d_out, int out_size, void* d_ws, size_t ws_size,
                              hipStream_t stream)
{
    const float* x      = (const float*)d_in[0];
    const int*   ei     = (const int*)d_in[1];
    const float* W1     = (const float*)d_in[2];
    const float* a_src1 = (const float*)d_in[3];
    const float* a_dst1 = (const float*)d_in[4];
    const float* b1     = (const float*)d_in[5];
    const float* W2     = (const float*)d_in[6];
    const float* a_src2 = (const float*)d_in[7];
    const float* a_dst2 = (const float*)d_in[8];
    const float* b2     = (const float*)d_in[9];
    float* out = (float*)d_out;

    const int n = in_sizes[0] / 256;     // 50000
    const int E = in_sizes[1] / 2;       // 1600000
    const int* src = ei;
    const int* dst = ei + E;

    // Workspace layout
    size_t N64 = (size_t)n * 64;
    size_t N8  = (size_t)n * 8;
    float* xl    = (float*)d_ws;            // N*64
    float* hbuf  = xl + N64;                // N*64
    float* asrc  = hbuf + N64;              // N*8
    float* adst  = asrc + N8;               // N*8
    int*   cnt   = (int*)(adst + N8);       // n
    int*   part  = cnt + n;                 // n
    int*   offs  = part + n;                // n+1
    int*   cursor= offs + n + 1;            // n
    int*   sums  = cursor + n;              // 64
    unsigned short* ssrc = (unsigned short*)(sums + 64);  // E (2B each)
    (void)ws_size; (void)n_in; (void)out_size;

    // ---------------- CSR build (graph shared by both layers) ----------------
    hipMemsetAsync(cnt, 0, n * sizeof(int), stream);
    hist_kernel<<<2048, 256, 0, stream>>>(dst, E, cnt);
    {
        int nb = (n + SCAN_BLK * SCAN_ELEM - 1) / (SCAN_BLK * SCAN_ELEM);  // 25
        scan1_kernel<<<nb, SCAN_BLK, 0, stream>>>(cnt, part, sums, n);
        scan2_kernel<<<1, 64, 0, stream>>>(sums, nb);
        scan3_kernel<<<(n + 255) / 256, 256, 0, stream>>>(part, sums, offs, cursor, n, E);
    }
    scatter_kernel<<<2048, 256, 0, stream>>>(src, dst, E, cursor, ssrc);

    // ---------------- Layer 1: 256 -> 8x8, concat, +b1, ELU ----------------
    node_transform<256, 8, 8><<<n, 64, 0, stream>>>(x, W1, a_src1, a_dst1,
                                                    xl, asrc, adst, n);
    aggregate_csr<8, 8, 1><<<(n + 3) / 4, 256, 0, stream>>>(offs, ssrc, asrc, adst,
                                                            xl, b1, hbuf, n);

    // ---------------- Layer 2: 64 -> 4x16, mean heads, +b2 ----------------
    node_transform<64, 4, 16><<<n, 64, 0, stream>>>(hbuf, W2, a_src2, a_dst2,
                                                    xl, asrc, adst, n);
    aggregate_csr<4, 16, 2><<<(n + 3) / 4, 256, 0, stream>>>(offs, ssrc, asrc, adst,
                                                             xl, b2, out, n);
}